// Round 2
// baseline (19.260 us; speedup 1.0000x reference)
//
#include <hip/hip_runtime.h>

// GRU single-step cell over N = B*A independent rows of 9 floats (col0 = h, cols1:9 = x).
// AoS-9 layout defeats per-instruction coalescing, so each block stages its
// 1024 rows (36 KB) into LDS via fully-coalesced float4 loads, then threads
// read their rows from LDS (padded stride -> conflict-free).

constexpr int BLOCK = 256;
constexpr int RPT   = 4;                  // rows per thread
constexpr int RPB   = BLOCK * RPT;        // 1024 rows per block
constexpr int F4PB  = RPB * 9 / 4;        // 2304 float4 per block
constexpr int F4PT  = F4PB / BLOCK;       // 9 float4 loads per thread
constexpr int CHUNK_F = RPT * 9 + 1;      // 37 floats: 36 data + 1 pad (odd stride -> <=2-way banks)

__global__ __launch_bounds__(BLOCK) void gru_cell_kernel(
    const float* __restrict__ in,    // (N, 9)
    const float* __restrict__ w_ih,  // (3, 8)
    const float* __restrict__ w_hh,  // (3, 1)
    const float* __restrict__ b_ih,  // (3,)
    const float* __restrict__ b_hh,  // (3,)
    const float* __restrict__ w_out, // (1, 1)
    const float* __restrict__ b_out, // (1,)
    float* __restrict__ out,         // (N,)
    int n_rows)
{
    __shared__ float lds[BLOCK * CHUNK_F];   // 37,888 B -> 4 blocks/CU (16 waves/CU)

    const int t = threadIdx.x;
    const int blk = blockIdx.x;
    const size_t f4_base = (size_t)blk * F4PB;

    // ---- Stage: 9 per-instruction-coalesced float4 loads per thread ----
    const float4* src = reinterpret_cast<const float4*>(in);
#pragma unroll
    for (int k = 0; k < F4PT; ++k) {
        const int j = k * BLOCK + t;             // block-local float4 index, lanes consecutive
        float4 v = src[f4_base + j];
        const int c = j / 9;                     // owning thread-chunk
        const int m = j - c * 9;                 // float4 slot within chunk
        float* dst = &lds[c * CHUNK_F + m * 4];
        dst[0] = v.x; dst[1] = v.y; dst[2] = v.z; dst[3] = v.w;
    }

    // Uniform-address weight loads (SGPR-broadcast).
    float wih[3][8];
#pragma unroll
    for (int g = 0; g < 3; ++g)
#pragma unroll
        for (int c = 0; c < 8; ++c)
            wih[g][c] = w_ih[g * 8 + c];
    const float whh0 = w_hh[0], whh1 = w_hh[1], whh2 = w_hh[2];
    const float bi0 = b_ih[0], bi1 = b_ih[1], bi2 = b_ih[2];
    const float bh0 = b_hh[0], bh1 = b_hh[1], bh2 = b_hh[2];
    const float wo = w_out[0], bo = b_out[0];

    __syncthreads();

    // ---- Compute: each thread owns 4 consecutive rows from its LDS chunk ----
    const float* chunk = &lds[t * CHUNK_F];
    float4 o;
    float* op = reinterpret_cast<float*>(&o);
#pragma unroll
    for (int r = 0; r < RPT; ++r) {
        const float* row = chunk + r * 9;
        const float h = row[0];
        float gi0 = bi0, gi1 = bi1, gi2 = bi2;
#pragma unroll
        for (int c = 0; c < 8; ++c) {
            const float x = row[1 + c];
            gi0 = fmaf(x, wih[0][c], gi0);
            gi1 = fmaf(x, wih[1][c], gi1);
            gi2 = fmaf(x, wih[2][c], gi2);
        }
        const float gh0 = fmaf(h, whh0, bh0);
        const float gh1 = fmaf(h, whh1, bh1);
        const float gh2 = fmaf(h, whh2, bh2);

        // sigmoid / tanh via v_exp_f32 (fast HW exp); tolerance is 8.4e-2 absolute.
        const float rg = 1.0f / (1.0f + __expf(-(gi0 + gh0)));
        const float z  = 1.0f / (1.0f + __expf(-(gi1 + gh1)));
        const float y  = fmaf(rg, gh2, gi2);
        const float nn = 2.0f / (1.0f + __expf(-2.0f * y)) - 1.0f;   // tanh(y)
        const float hn = (1.0f - z) * nn + z * h;
        op[r] = fmaf(hn, wo, bo);
    }

    // ---- Coalesced float4 store: thread t writes rows 4t..4t+3 ----
    const size_t out_f4 = (size_t)blk * BLOCK + t;
    if ((out_f4 + 1) * 4 <= (size_t)n_rows)
        reinterpret_cast<float4*>(out)[out_f4] = o;
}

extern "C" void kernel_launch(void* const* d_in, const int* in_sizes, int n_in,
                              void* d_out, int out_size, void* d_ws, size_t ws_size,
                              hipStream_t stream) {
    (void)n_in; (void)d_ws; (void)ws_size; (void)in_sizes;
    const float* in    = (const float*)d_in[0];
    const float* w_ih  = (const float*)d_in[1];
    const float* w_hh  = (const float*)d_in[2];
    const float* b_ih  = (const float*)d_in[3];
    const float* b_hh  = (const float*)d_in[4];
    const float* w_out = (const float*)d_in[5];
    const float* b_out = (const float*)d_in[6];
    float* out = (float*)d_out;

    const int n_rows = out_size;                  // B*A = 2,097,152 (divisible by 1024)
    const int grid = (n_rows + RPB - 1) / RPB;    // 2048 blocks

    gru_cell_kernel<<<grid, BLOCK, 0, stream>>>(in, w_ih, w_hh, b_ih, b_hh,
                                                w_out, b_out, out, n_rows);
}